// Round 8
// baseline (494.412 us; speedup 1.0000x reference)
//
#include <hip/hip_runtime.h>
#include <hip/hip_cooperative_groups.h>
#include <hip/hip_bf16.h>
#include <math.h>

namespace cg = cooperative_groups;

#define NN 100000
#define DD 384
#define HH 128
#define KK 5

typedef __attribute__((ext_vector_type(8))) short short8;
typedef __attribute__((ext_vector_type(4))) float f32x4;

constexpr float INIT_VAL = 1.4142135623730951e-3f; // 1/sqrt(N*K)
constexpr float RSQRT5   = 0.44721359549995793f;   // 1/sqrt(5)

// split f32 -> bf16 hi + bf16 lo (truncation; |x - hi - lo| <= 2^-16 |x|)
__device__ __forceinline__ void split_bf16(float x, ushort& hi, ushort& lo) {
    unsigned xb = __float_as_uint(x);
    hi = (ushort)(xb >> 16);
    float hif = __uint_as_float(((unsigned)hi) << 16);
    lo = (ushort)(__float_as_uint(x - hif) >> 16);
}

// ---------------- fused prep ----------------
// block 0: PARALLEL fold qv @ W1[384:768] into bias (256 thr + LDS reduce); zero ssp
// blocks 1..24: pack W1[0:384] into MFMA B-fragment layout, bf16 hi/lo
// blocks 25..415: transpose nbr to SoA + zero the three scatter buffers
__global__ __launch_bounds__(256) void prep_kernel(
    const float* __restrict__ qv, const float* __restrict__ W1,
    const float* __restrict__ b1, const int* __restrict__ nbr,
    float* __restrict__ b1p, ushort* __restrict__ W1h, ushort* __restrict__ W1l,
    int* __restrict__ nbrT, float* __restrict__ sA, float* __restrict__ sB,
    float* __restrict__ sC, float* __restrict__ ssp) {
    const int b = blockIdx.x, tid = threadIdx.x;
    if (b == 0) {
        __shared__ float part[256];
        const int h = tid & 127, half = tid >> 7;
        float s = 0.f;
        const float* Wq = W1 + (size_t)(DD + half * 192) * HH + h;
        const float* qh = qv + half * 192;
#pragma unroll 8
        for (int k = 0; k < 192; ++k)
            s = fmaf(qh[k], Wq[(size_t)k * HH], s);
        part[tid] = s;
        __syncthreads();
        if (tid < HH) b1p[tid] = part[tid] + part[tid + 128] + b1[tid];
        if (tid == 0) ssp[0] = 0.f;
    } else if (b <= 24) {
        int t = (b - 1) * 256 + tid;       // t = (c*12 + ks)*64 + lane, t < 6144
        int l = t & 63;
        int ks = (t >> 6) % 12;
        int c = (t >> 6) / 12;
        int k0 = ks * 32 + ((l >> 4) << 3);
        int col = c * 16 + (l & 15);
#pragma unroll
        for (int e = 0; e < 8; ++e) {
            ushort hv, lv;
            split_bf16(W1[(size_t)(k0 + e) * HH + col], hv, lv);
            W1h[(size_t)t * 8 + e] = hv;
            W1l[(size_t)t * 8 + e] = lv;
        }
    } else {
        int i = (b - 25) * 256 + tid;
        if (i < NN) {
#pragma unroll
            for (int j = 0; j < KK; ++j) {
                nbrT[j * NN + i] = nbr[i * KK + j];
                sA[j * NN + i] = 0.f;
                sB[j * NN + i] = 0.f;
                sC[j * NN + i] = 0.f;
            }
        }
    }
}

// ---------------- MFMA MLP: R3 pipeline + M-loop over 3 node-tiles ----------------
// grid 521 blocks x 3 tiles of 64 nodes. 4 waves (2 M-halves x 2 hidden-halves).
// Per k-subtile: reg-prefetch next subtile's A (T14), LDS hi/lo staging (XOR swz),
// B-fragment dbuf from L2. Epilogue per tile fuses walk step 1.
__global__ __launch_bounds__(256, 2) void mlp_mfma_kernel(
    const float* __restrict__ emb, const ushort* __restrict__ W1h,
    const ushort* __restrict__ W1l, const float* __restrict__ b1p,
    const float* __restrict__ W2, const float* __restrict__ b2,
    const int* __restrict__ nbrT, float* __restrict__ gout /* [KK][NN] */,
    float* __restrict__ sA) {
    __shared__ __align__(16) ushort Ah[64 * 128];  // 16 KB
    __shared__ __align__(16) ushort Al[64 * 128];  // 16 KB
    __shared__ float pbuf[64][2][8];               // 4 KB

    const int tid = threadIdx.x;
    const int lane = tid & 63;
    const int wid = tid >> 6;
    const int wm = wid >> 1;   // M half (32 rows)
    const int wn = wid & 1;    // hidden half (64 cols)

    float4 aregs[8];
    auto issueA = [&](int step) {   // step = tile*3 + k-subtile, 0..8
        const int tileBase = (blockIdx.x * 3 + step / 3) * 64;
        const int kbase = (step % 3) * 128;
#pragma unroll
        for (int i = 0; i < 8; ++i) {
            int idx = tid + i * 256;
            int r = idx >> 5, c = idx & 31;
            int node = min(tileBase + r, NN - 1);
            aregs[i] = *reinterpret_cast<const float4*>(&emb[(size_t)node * DD + kbase + c * 4]);
        }
    };
    auto writeLDS = [&]() {
#pragma unroll
        for (int i = 0; i < 8; ++i) {
            int idx = tid + i * 256;
            int r = idx >> 5, c = idx & 31;
            ushort4 hv, lv;
            split_bf16(aregs[i].x, hv.x, lv.x);
            split_bf16(aregs[i].y, hv.y, lv.y);
            split_bf16(aregs[i].z, hv.z, lv.z);
            split_bf16(aregs[i].w, hv.w, lv.w);
            int byte = (r * 256 + c * 8) ^ ((r & 7) << 4);
            *reinterpret_cast<ushort4*>(reinterpret_cast<char*>(Ah) + byte) = hv;
            *reinterpret_cast<ushort4*>(reinterpret_cast<char*>(Al) + byte) = lv;
        }
    };

    // tile-invariant epilogue constants
    float b1v[4], w2v[4][KK];
#pragma unroll
    for (int nt = 0; nt < 4; ++nt) {
        int h = wn * 64 + nt * 16 + (lane & 15);
        b1v[nt] = b1p[h];
#pragma unroll
        for (int j = 0; j < KK; ++j) w2v[nt][j] = W2[h * KK + j];
    }

    issueA(0);

    for (int tt = 0; tt < 3; ++tt) {
        const int blkBase = (blockIdx.x * 3 + tt) * 64;
        f32x4 acc[2][4];
#pragma unroll
        for (int mt = 0; mt < 2; ++mt)
#pragma unroll
            for (int nt = 0; nt < 4; ++nt) acc[mt][nt] = (f32x4){0.f, 0.f, 0.f, 0.f};

#pragma unroll
        for (int t = 0; t < 3; ++t) {
            writeLDS();
            int stepNext = tt * 3 + t + 1;
            if (stepNext < 9) issueA(stepNext);   // in flight across compute phase
            __syncthreads();

            short8 bh[2][4], bl[2][4], ah[2][2], al[2][2];
            auto loadB = [&](int kt, int s) {
                int ks = t * 4 + kt;
#pragma unroll
                for (int nt = 0; nt < 4; ++nt) {
                    size_t off = ((size_t)((wn * 4 + nt) * 12 + ks) * 64 + lane) * 8;
                    bh[s][nt] = *reinterpret_cast<const short8*>(&W1h[off]);
                    bl[s][nt] = *reinterpret_cast<const short8*>(&W1l[off]);
                }
            };
            auto loadA = [&](int kt, int s) {
#pragma unroll
                for (int mt = 0; mt < 2; ++mt) {
                    int row = wm * 32 + mt * 16 + (lane & 15);
                    int byte = (row * 256 + kt * 64 + ((lane >> 4) << 4)) ^ ((row & 7) << 4);
                    ah[s][mt] = *reinterpret_cast<const short8*>(reinterpret_cast<const char*>(Ah) + byte);
                    al[s][mt] = *reinterpret_cast<const short8*>(reinterpret_cast<const char*>(Al) + byte);
                }
            };

            loadB(0, 0);
            loadA(0, 0);
#pragma unroll
            for (int kt = 0; kt < 4; ++kt) {
                const int cur = kt & 1, nxt = cur ^ 1;
                if (kt < 3) {
                    loadB(kt + 1, nxt);
                    loadA(kt + 1, nxt);
                }
#pragma unroll
                for (int mt = 0; mt < 2; ++mt)
#pragma unroll
                    for (int nt = 0; nt < 4; ++nt) {
                        acc[mt][nt] = __builtin_amdgcn_mfma_f32_16x16x32_bf16(ah[cur][mt], bh[cur][nt], acc[mt][nt], 0, 0, 0);
                        acc[mt][nt] = __builtin_amdgcn_mfma_f32_16x16x32_bf16(al[cur][mt], bh[cur][nt], acc[mt][nt], 0, 0, 0);
                        acc[mt][nt] = __builtin_amdgcn_mfma_f32_16x16x32_bf16(ah[cur][mt], bl[cur][nt], acc[mt][nt], 0, 0, 0);
                    }
            }
            __syncthreads();   // release LDS for next subtile
        }

        // ---- per-tile epilogue: bias+relu, xW2, 16-lane reduce, g + fused walk1 ----
#pragma unroll
        for (int mt = 0; mt < 2; ++mt) {
            float p[4][KK];
#pragma unroll
            for (int r = 0; r < 4; ++r)
#pragma unroll
                for (int j = 0; j < KK; ++j) p[r][j] = 0.f;
#pragma unroll
            for (int nt = 0; nt < 4; ++nt)
#pragma unroll
                for (int r = 0; r < 4; ++r) {
                    float v = fmaxf(acc[mt][nt][r] + b1v[nt], 0.f);
#pragma unroll
                    for (int j = 0; j < KK; ++j) p[r][j] = fmaf(v, w2v[nt][j], p[r][j]);
                }
#pragma unroll
            for (int off = 1; off < 16; off <<= 1)
#pragma unroll
                for (int r = 0; r < 4; ++r)
#pragma unroll
                    for (int j = 0; j < KK; ++j) p[r][j] += __shfl_xor(p[r][j], off, 64);
            if ((lane & 15) == 0) {
                int rowbase = wm * 32 + mt * 16 + (lane >> 4) * 4;
#pragma unroll
                for (int r = 0; r < 4; ++r)
#pragma unroll
                    for (int j = 0; j < KK; ++j) pbuf[rowbase + r][wn][j] = p[r][j];
            }
        }
        __syncthreads();
        if (tid < 64) {
            int node = blkBase + tid;
            if (node < NN) {
                float a[KK], an2 = 0.f;
#pragma unroll
                for (int j = 0; j < KK; ++j) {
                    a[j] = pbuf[tid][0][j] + pbuf[tid][1][j] + b2[j];
                    an2 = fmaf(a[j], a[j], an2);
                }
                float an = sqrtf(an2);
                bool valid = (an2 > 0.f) && isfinite(an);
                float g5[KK], ssum = 0.f;
#pragma unroll
                for (int j = 0; j < KK; ++j) {
                    g5[j] = valid ? (a[j] / an) : RSQRT5;
                    gout[j * NN + node] = g5[j];
                    ssum += g5[j];
                }
                float d = ssum * INIT_VAL;   // fused walk step 1 (uniform state)
#pragma unroll
                for (int j = 0; j < KK; ++j)
                    atomicAdd(&sA[j * NN + nbrT[j * NN + node]], g5[j] * d);
            }
        }
        __syncthreads();   // pbuf safe for next tile
    }
}

// ---------------- cooperative tail: walk2 + walk3 + norm + finalize ----------------
__global__ __launch_bounds__(256) void walk_tail_kernel(
    const float* __restrict__ g, const int* __restrict__ nbrT,
    const float* __restrict__ sA, float* __restrict__ sB, float* __restrict__ sC,
    float* __restrict__ ssp, float* __restrict__ out) {
    cg::grid_group grid = cg::this_grid();
    const int i = blockIdx.x * blockDim.x + threadIdx.x;
    const bool act = i < NN;
    float gj[KK];
    int nb[KK];
    if (act) {
        float d = 0.f;
#pragma unroll
        for (int j = 0; j < KK; ++j) {
            gj[j] = g[j * NN + i];
            nb[j] = nbrT[j * NN + i];
            d = fmaf(gj[j], sA[j * NN + i], d);
        }
#pragma unroll
        for (int j = 0; j < KK; ++j)
            atomicAdd(&sB[j * NN + nb[j]], gj[j] * d);
    }
    __threadfence();
    grid.sync();
    if (act) {
        float d = 0.f;
#pragma unroll
        for (int j = 0; j < KK; ++j) d = fmaf(gj[j], sB[j * NN + i], d);
#pragma unroll
        for (int j = 0; j < KK; ++j)
            atomicAdd(&sC[j * NN + nb[j]], gj[j] * d);
    }
    __threadfence();
    grid.sync();
    float s = 0.f;
    if (act) {
#pragma unroll
        for (int j = 0; j < KK; ++j) {
            float x = sC[j * NN + i];
            s = fmaf(x, x, s);
        }
    }
#pragma unroll
    for (int off = 32; off > 0; off >>= 1) s += __shfl_xor(s, off, 64);
    if ((threadIdx.x & 63) == 0) atomicAdd(ssp, s);
    __threadfence();
    grid.sync();
    if (act) {
        float nrm = sqrtf(ssp[0]);
        float t = 0.f;
#pragma unroll
        for (int j = 0; j < KK; ++j) t += fabsf(sC[j * NN + i]);
        out[i] = (nrm > 0.f) ? (t / nrm) : (KK * INIT_VAL);
    }
}

extern "C" void kernel_launch(void* const* d_in, const int* in_sizes, int n_in,
                              void* d_out, int out_size, void* d_ws, size_t ws_size,
                              hipStream_t stream) {
    const float* emb = (const float*)d_in[0];
    const float* qv  = (const float*)d_in[1];
    const float* W1  = (const float*)d_in[2];
    const float* b1  = (const float*)d_in[3];
    const float* W2  = (const float*)d_in[4];
    const float* b2  = (const float*)d_in[5];
    const int*   nbr = (const int*)d_in[6];
    float* out = (float*)d_out;

    char* ws = (char*)d_ws;
    size_t off = 0;
    auto alloc = [&](size_t bytes) {
        char* p = ws + off;
        off += (bytes + 255) & ~(size_t)255;
        return p;
    };
    float*  b1p  = (float*)alloc(HH * sizeof(float));
    ushort* W1h  = (ushort*)alloc((size_t)DD * HH * sizeof(ushort));
    ushort* W1l  = (ushort*)alloc((size_t)DD * HH * sizeof(ushort));
    float*  gbuf = (float*)alloc((size_t)KK * NN * sizeof(float));
    int*    nbrT = (int*)  alloc((size_t)KK * NN * sizeof(int));
    float*  sA   = (float*)alloc((size_t)KK * NN * sizeof(float));
    float*  sB   = (float*)alloc((size_t)KK * NN * sizeof(float));
    float*  sC   = (float*)alloc((size_t)KK * NN * sizeof(float));
    float*  ssp  = (float*)alloc(sizeof(float));

    const int nblk = (NN + 255) / 256;   // 391

    prep_kernel<<<25 + nblk, 256, 0, stream>>>(qv, W1, b1, nbr, b1p, W1h, W1l,
                                               nbrT, sA, sB, sC, ssp);
    // 521 blocks x 3 tiles of 64 nodes = 1563 tiles (covers 100032 >= NN)
    mlp_mfma_kernel<<<521, 256, 0, stream>>>(emb, W1h, W1l, b1p, W2, b2,
                                             nbrT, gbuf, sA);

    void* args[] = {(void*)&gbuf, (void*)&nbrT, (void*)&sA, (void*)&sB,
                    (void*)&sC, (void*)&ssp, (void*)&out};
    hipLaunchCooperativeKernel((void*)walk_tail_kernel, dim3(nblk), dim3(256),
                               args, 0, stream);
}

// Round 9
// 177.907 us; speedup vs baseline: 2.7790x; 2.7790x over previous
//
#include <hip/hip_runtime.h>
#include <hip/hip_bf16.h>
#include <math.h>

#define NN 100000
#define DD 384
#define HH 128
#define KK 5

typedef __attribute__((ext_vector_type(8))) short short8;
typedef __attribute__((ext_vector_type(4))) float f32x4;

constexpr float INIT_VAL = 1.4142135623730951e-3f; // 1/sqrt(N*K)
constexpr float RSQRT5   = 0.44721359549995793f;   // 1/sqrt(5)

// split f32 -> bf16 hi + bf16 lo (truncation; |x - hi - lo| <= 2^-16 |x|)
__device__ __forceinline__ void split_bf16(float x, ushort& hi, ushort& lo) {
    unsigned xb = __float_as_uint(x);
    hi = (ushort)(xb >> 16);
    float hif = __uint_as_float(((unsigned)hi) << 16);
    lo = (ushort)(__float_as_uint(x - hif) >> 16);
}

// ---------------- fused prep ----------------
// block 0: PARALLEL fold qv @ W1[384:768] into bias; zero ssp
// blocks 1..24: pack W1[0:384] into B-fragment layout bf16 hi/lo
// blocks 25..: transpose nbr to SoA + zero the three scatter buffers
__global__ __launch_bounds__(256) void prep_kernel(
    const float* __restrict__ qv, const float* __restrict__ W1,
    const float* __restrict__ b1, const int* __restrict__ nbr,
    float* __restrict__ b1p, ushort* __restrict__ W1h, ushort* __restrict__ W1l,
    int* __restrict__ nbrT, float* __restrict__ sA, float* __restrict__ sB,
    float* __restrict__ sC, float* __restrict__ ssp) {
    const int b = blockIdx.x, tid = threadIdx.x;
    if (b == 0) {
        __shared__ float part[256];
        const int h = tid & 127, half = tid >> 7;
        float s = 0.f;
        const float* Wq = W1 + (size_t)(DD + half * 192) * HH + h;
        const float* qh = qv + half * 192;
#pragma unroll 8
        for (int k = 0; k < 192; ++k)
            s = fmaf(qh[k], Wq[(size_t)k * HH], s);
        part[tid] = s;
        __syncthreads();
        if (tid < HH) b1p[tid] = part[tid] + part[tid + 128] + b1[tid];
        if (tid == 0) ssp[0] = 0.f;
    } else if (b <= 24) {
        int t = (b - 1) * 256 + tid;       // t = (c*12 + ks)*64 + lane, t < 6144
        int l = t & 63;
        int ks = (t >> 6) % 12;
        int c = (t >> 6) / 12;
        int k0 = ks * 32 + ((l >> 4) << 3);
        int col = c * 16 + (l & 15);
#pragma unroll
        for (int e = 0; e < 8; ++e) {
            ushort hv, lv;
            split_bf16(W1[(size_t)(k0 + e) * HH + col], hv, lv);
            W1h[(size_t)t * 8 + e] = hv;
            W1l[(size_t)t * 8 + e] = lv;
        }
    } else {
        int i = (b - 25) * 256 + tid;
        if (i < NN) {
#pragma unroll
            for (int j = 0; j < KK; ++j) {
                nbrT[j * NN + i] = nbr[i * KK + j];
                sA[j * NN + i] = 0.f;
                sB[j * NN + i] = 0.f;
                sC[j * NN + i] = 0.f;
            }
        }
    }
}

// ---------------- GEMM only: h = emb x W1 (hi/lo MFMA), raw f32 out ----------------
// R3's proven structure, epilogue removed. 1563 blocks x 64-node tile.
__global__ __launch_bounds__(256, 2) void gemm_kernel(
    const float* __restrict__ emb, const ushort* __restrict__ W1h,
    const ushort* __restrict__ W1l, float* __restrict__ hbuf /* [NN][HH] */) {
    __shared__ __align__(16) ushort Ah[64 * 128];  // 16 KB
    __shared__ __align__(16) ushort Al[64 * 128];  // 16 KB

    const int tid = threadIdx.x;
    const int lane = tid & 63;
    const int wid = tid >> 6;
    const int wm = wid >> 1;   // M half (32 rows)
    const int wn = wid & 1;    // hidden half (64 cols)
    const int blkBase = blockIdx.x * 64;

    f32x4 acc[2][4];
#pragma unroll
    for (int mt = 0; mt < 2; ++mt)
#pragma unroll
        for (int nt = 0; nt < 4; ++nt) acc[mt][nt] = (f32x4){0.f, 0.f, 0.f, 0.f};

    float4 aregs[8];
    auto issueA = [&](int t) {
#pragma unroll
        for (int i = 0; i < 8; ++i) {
            int idx = tid + i * 256;
            int r = idx >> 5, c = idx & 31;
            int node = min(blkBase + r, NN - 1);
            aregs[i] = *reinterpret_cast<const float4*>(&emb[(size_t)node * DD + t * 128 + c * 4]);
        }
    };
    auto writeLDS = [&]() {
#pragma unroll
        for (int i = 0; i < 8; ++i) {
            int idx = tid + i * 256;
            int r = idx >> 5, c = idx & 31;
            ushort4 hv, lv;
            split_bf16(aregs[i].x, hv.x, lv.x);
            split_bf16(aregs[i].y, hv.y, lv.y);
            split_bf16(aregs[i].z, hv.z, lv.z);
            split_bf16(aregs[i].w, hv.w, lv.w);
            int byte = (r * 256 + c * 8) ^ ((r & 7) << 4);
            *reinterpret_cast<ushort4*>(reinterpret_cast<char*>(Ah) + byte) = hv;
            *reinterpret_cast<ushort4*>(reinterpret_cast<char*>(Al) + byte) = lv;
        }
    };

    issueA(0);
    writeLDS();
    __syncthreads();

#pragma unroll
    for (int t = 0; t < 3; ++t) {
        if (t < 2) issueA(t + 1);  // in flight across the whole compute phase

        short8 bh[2][4], bl[2][4], ah[2][2], al[2][2];
        auto loadB = [&](int kt, int s) {
            int ks = t * 4 + kt;
#pragma unroll
            for (int nt = 0; nt < 4; ++nt) {
                size_t off = ((size_t)((wn * 4 + nt) * 12 + ks) * 64 + lane) * 8;
                bh[s][nt] = *reinterpret_cast<const short8*>(&W1h[off]);
                bl[s][nt] = *reinterpret_cast<const short8*>(&W1l[off]);
            }
        };
        auto loadA = [&](int kt, int s) {
#pragma unroll
            for (int mt = 0; mt < 2; ++mt) {
                int row = wm * 32 + mt * 16 + (lane & 15);
                int byte = (row * 256 + kt * 64 + ((lane >> 4) << 4)) ^ ((row & 7) << 4);
                ah[s][mt] = *reinterpret_cast<const short8*>(reinterpret_cast<const char*>(Ah) + byte);
                al[s][mt] = *reinterpret_cast<const short8*>(reinterpret_cast<const char*>(Al) + byte);
            }
        };

        loadB(0, 0);
        loadA(0, 0);
#pragma unroll
        for (int kt = 0; kt < 4; ++kt) {
            const int cur = kt & 1, nxt = cur ^ 1;
            if (kt < 3) {
                loadB(kt + 1, nxt);
                loadA(kt + 1, nxt);
            }
#pragma unroll
            for (int mt = 0; mt < 2; ++mt)
#pragma unroll
                for (int nt = 0; nt < 4; ++nt) {
                    acc[mt][nt] = __builtin_amdgcn_mfma_f32_16x16x32_bf16(ah[cur][mt], bh[cur][nt], acc[mt][nt], 0, 0, 0);
                    acc[mt][nt] = __builtin_amdgcn_mfma_f32_16x16x32_bf16(al[cur][mt], bh[cur][nt], acc[mt][nt], 0, 0, 0);
                    acc[mt][nt] = __builtin_amdgcn_mfma_f32_16x16x32_bf16(ah[cur][mt], bl[cur][nt], acc[mt][nt], 0, 0, 0);
                }
        }

        if (t < 2) {
            __syncthreads();
            writeLDS();
            __syncthreads();
        }
    }

    // raw h writeback from MFMA C layout: col=lane&15, row=(lane>>4)*4+r
#pragma unroll
    for (int mt = 0; mt < 2; ++mt) {
        int node = blkBase + wm * 32 + mt * 16 + ((lane >> 4) << 2);
#pragma unroll
        for (int nt = 0; nt < 4; ++nt) {
            int h = wn * 64 + nt * 16 + (lane & 15);
#pragma unroll
            for (int r = 0; r < 4; ++r) {
                if (node + r < NN)
                    hbuf[(size_t)(node + r) * HH + h] = acc[mt][nt][r];
            }
        }
    }
}

// ---------------- gv: a = relu(h+b1) x W2 + b2; g = a/||a||; fused walk1 ----------------
__global__ __launch_bounds__(256) void gv_kernel(
    const float* __restrict__ hbuf, const float* __restrict__ b1p,
    const float* __restrict__ W2, const float* __restrict__ b2,
    const int* __restrict__ nbrT, float* __restrict__ gout /* [KK][NN] */,
    float* __restrict__ sA) {
    int node = blockIdx.x * 256 + threadIdx.x;
    if (node >= NN) return;
    const float* hr = hbuf + (size_t)node * HH;
    float p[KK] = {0.f, 0.f, 0.f, 0.f, 0.f};
#pragma unroll 4
    for (int c = 0; c < HH / 8; ++c) {
        float4 x = *reinterpret_cast<const float4*>(hr + c * 8);
        float4 y = *reinterpret_cast<const float4*>(hr + c * 8 + 4);
        float hv[8] = {x.x, x.y, x.z, x.w, y.x, y.y, y.z, y.w};
#pragma unroll
        for (int e = 0; e < 8; ++e) {
            int h = c * 8 + e;
            float v = fmaxf(hv[e] + b1p[h], 0.f);   // b1p/W2 wave-uniform loads
#pragma unroll
            for (int j = 0; j < KK; ++j) p[j] = fmaf(v, W2[h * KK + j], p[j]);
        }
    }
    float a[KK], an2 = 0.f;
#pragma unroll
    for (int j = 0; j < KK; ++j) {
        a[j] = p[j] + b2[j];
        an2 = fmaf(a[j], a[j], an2);
    }
    float an = sqrtf(an2);
    bool valid = (an2 > 0.f) && isfinite(an);
    float g5[KK], ssum = 0.f;
#pragma unroll
    for (int j = 0; j < KK; ++j) {
        g5[j] = valid ? (a[j] / an) : RSQRT5;
        gout[j * NN + node] = g5[j];
        ssum += g5[j];
    }
    // fused walk step 1: state uniform INIT_VAL -> d = INIT * sum(g)
    float d = ssum * INIT_VAL;
#pragma unroll
    for (int j = 0; j < KK; ++j)
        atomicAdd(&sA[j * NN + nbrT[j * NN + node]], g5[j] * d);
}

// ---------------- walk step: s_p = g (g.u); scatter-add ----------------
__global__ void walk_step_kernel(const float* __restrict__ g, const int* __restrict__ nbrT,
                                 const float* __restrict__ u, float* __restrict__ v) {
    int i = blockIdx.x * blockDim.x + threadIdx.x;
    if (i >= NN) return;
    float gj[KK], d = 0.f;
#pragma unroll
    for (int j = 0; j < KK; ++j) {
        gj[j] = g[j * NN + i];
        d = fmaf(gj[j], u[j * NN + i], d);
    }
#pragma unroll
    for (int j = 0; j < KK; ++j)
        atomicAdd(&v[j * NN + nbrT[j * NN + i]], gj[j] * d);
}

// ---------------- global sum of squares (float4) ----------------
__global__ void norm_reduce_kernel(const float* __restrict__ u, float* __restrict__ ss) {
    int i = blockIdx.x * blockDim.x + threadIdx.x;
    const int total4 = (KK * NN) / 4;  // 125000
    float s = 0.f;
    for (int idx = i; idx < total4; idx += gridDim.x * blockDim.x) {
        float4 x = reinterpret_cast<const float4*>(u)[idx];
        s = fmaf(x.x, x.x, s);
        s = fmaf(x.y, x.y, s);
        s = fmaf(x.z, x.z, s);
        s = fmaf(x.w, x.w, s);
    }
#pragma unroll
    for (int off = 32; off > 0; off >>= 1) s += __shfl_xor(s, off, 64);
    if ((threadIdx.x & 63) == 0) atomicAdd(ss, s);
}

// ---------------- out[i] = sum_j |u[j][i]| / ||u|| ----------------
__global__ void finalize_kernel(const float* __restrict__ u, const float* __restrict__ ss,
                                float* __restrict__ out) {
    int i = blockIdx.x * blockDim.x + threadIdx.x;
    if (i >= NN) return;
    float s = 0.f;
#pragma unroll
    for (int j = 0; j < KK; ++j) s += fabsf(u[j * NN + i]);
    float nrm = sqrtf(*ss);
    out[i] = (nrm > 0.f) ? (s / nrm) : (KK * INIT_VAL);
}

extern "C" void kernel_launch(void* const* d_in, const int* in_sizes, int n_in,
                              void* d_out, int out_size, void* d_ws, size_t ws_size,
                              hipStream_t stream) {
    const float* emb = (const float*)d_in[0];
    const float* qv  = (const float*)d_in[1];
    const float* W1  = (const float*)d_in[2];
    const float* b1  = (const float*)d_in[3];
    const float* W2  = (const float*)d_in[4];
    const float* b2  = (const float*)d_in[5];
    const int*   nbr = (const int*)d_in[6];
    float* out = (float*)d_out;

    char* ws = (char*)d_ws;
    size_t off = 0;
    auto alloc = [&](size_t bytes) {
        char* p = ws + off;
        off += (bytes + 255) & ~(size_t)255;
        return p;
    };
    float*  b1p  = (float*)alloc(HH * sizeof(float));
    ushort* W1h  = (ushort*)alloc((size_t)DD * HH * sizeof(ushort));
    ushort* W1l  = (ushort*)alloc((size_t)DD * HH * sizeof(ushort));
    float*  gbuf = (float*)alloc((size_t)KK * NN * sizeof(float));
    int*    nbrT = (int*)  alloc((size_t)KK * NN * sizeof(int));
    float*  sA   = (float*)alloc((size_t)KK * NN * sizeof(float));
    float*  sB   = (float*)alloc((size_t)KK * NN * sizeof(float));
    float*  sC   = (float*)alloc((size_t)KK * NN * sizeof(float));
    float*  ssp  = (float*)alloc(sizeof(float));
    float*  hbuf = (float*)alloc((size_t)NN * HH * sizeof(float));  // 51.2 MB

    const int nblk = (NN + 255) / 256;   // 391

    prep_kernel<<<25 + nblk, 256, 0, stream>>>(qv, W1, b1, nbr, b1p, W1h, W1l,
                                               nbrT, sA, sB, sC, ssp);
    gemm_kernel<<<(NN + 63) / 64, 256, 0, stream>>>(emb, W1h, W1l, hbuf);
    gv_kernel<<<nblk, 256, 0, stream>>>(hbuf, b1p, W2, b2, nbrT, gbuf, sA);

    walk_step_kernel<<<nblk, 256, 0, stream>>>(gbuf, nbrT, sA, sB);
    walk_step_kernel<<<nblk, 256, 0, stream>>>(gbuf, nbrT, sB, sC);

    norm_reduce_kernel<<<512, 256, 0, stream>>>(sC, ssp);
    finalize_kernel<<<nblk, 256, 0, stream>>>(sC, ssp, out);
}

// Round 10
// 174.743 us; speedup vs baseline: 2.8294x; 1.0181x over previous
//
#include <hip/hip_runtime.h>
#include <hip/hip_bf16.h>
#include <math.h>

#define NN 100000
#define DD 384
#define HH 128
#define KK 5

typedef __attribute__((ext_vector_type(8))) short short8;
typedef __attribute__((ext_vector_type(4))) float f32x4;

constexpr float INIT_VAL = 1.4142135623730951e-3f; // 1/sqrt(N*K)
constexpr float RSQRT5   = 0.44721359549995793f;   // 1/sqrt(5)

// split f32 -> bf16 hi + bf16 lo (truncation; |x - hi - lo| <= 2^-16 |x|)
__device__ __forceinline__ void split_bf16(float x, ushort& hi, ushort& lo) {
    unsigned xb = __float_as_uint(x);
    hi = (ushort)(xb >> 16);
    float hif = __uint_as_float(((unsigned)hi) << 16);
    lo = (ushort)(__float_as_uint(x - hif) >> 16);
}

// ---------------- fused prep ----------------
__global__ __launch_bounds__(256) void prep_kernel(
    const float* __restrict__ qv, const float* __restrict__ W1,
    const float* __restrict__ b1, const int* __restrict__ nbr,
    float* __restrict__ b1p, ushort* __restrict__ W1h, ushort* __restrict__ W1l,
    int* __restrict__ nbrT, float* __restrict__ sA, float* __restrict__ sB,
    float* __restrict__ sC, float* __restrict__ ssp) {
    const int b = blockIdx.x, tid = threadIdx.x;
    if (b == 0) {
        __shared__ float part[256];
        const int h = tid & 127, half = tid >> 7;
        float s = 0.f;
        const float* Wq = W1 + (size_t)(DD + half * 192) * HH + h;
        const float* qh = qv + half * 192;
#pragma unroll 8
        for (int k = 0; k < 192; ++k)
            s = fmaf(qh[k], Wq[(size_t)k * HH], s);
        part[tid] = s;
        __syncthreads();
        if (tid < HH) b1p[tid] = part[tid] + part[tid + 128] + b1[tid];
        if (tid == 0) ssp[0] = 0.f;
    } else if (b <= 24) {
        int t = (b - 1) * 256 + tid;       // t = (c*12 + ks)*64 + lane, t < 6144
        int l = t & 63;
        int ks = (t >> 6) % 12;
        int c = (t >> 6) / 12;
        int k0 = ks * 32 + ((l >> 4) << 3);
        int col = c * 16 + (l & 15);
#pragma unroll
        for (int e = 0; e < 8; ++e) {
            ushort hv, lv;
            split_bf16(W1[(size_t)(k0 + e) * HH + col], hv, lv);
            W1h[(size_t)t * 8 + e] = hv;
            W1l[(size_t)t * 8 + e] = lv;
        }
    } else {
        int i = (b - 25) * 256 + tid;
        if (i < NN) {
#pragma unroll
            for (int j = 0; j < KK; ++j) {
                nbrT[j * NN + i] = nbr[i * KK + j];
                sA[j * NN + i] = 0.f;
                sB[j * NN + i] = 0.f;
                sC[j * NN + i] = 0.f;
            }
        }
    }
}

// ---------------- fused MFMA MLP: asm-pinned A staging + epilogue + walk1 ----------------
// R9's GEMM structure; the 8 A-tile loads per thread are inline-asm
// global_load_dwordx4 pinned in VGPRs, in flight across the whole compute phase.
__global__ __launch_bounds__(256) void mlp_mfma_kernel(
    const float* __restrict__ emb, const ushort* __restrict__ W1h,
    const ushort* __restrict__ W1l, const float* __restrict__ b1p,
    const float* __restrict__ W2, const float* __restrict__ b2,
    const int* __restrict__ nbrT, float* __restrict__ gout /* [KK][NN] */,
    float* __restrict__ sA) {
    __shared__ __align__(16) ushort Ah[64 * 128];  // 16 KB
    __shared__ __align__(16) ushort Al[64 * 128];  // 16 KB
    __shared__ float pbuf[64][2][8];               // 4 KB

    const int tid = threadIdx.x;
    const int lane = tid & 63;
    const int wid = tid >> 6;
    const int wm = wid >> 1;   // M half (32 rows)
    const int wn = wid & 1;    // hidden half (64 cols)
    const int blkBase = blockIdx.x * 64;

    f32x4 acc[2][4];
#pragma unroll
    for (int mt = 0; mt < 2; ++mt)
#pragma unroll
        for (int nt = 0; nt < 4; ++nt) acc[mt][nt] = (f32x4){0.f, 0.f, 0.f, 0.f};

    float4 aregs[8];
    // issue 8 asm loads; results pinned in VGPRs until writeLDS consumes them
    auto issueA = [&](int t) {
#pragma unroll
        for (int i = 0; i < 8; ++i) {
            int idx = tid + i * 256;
            int r = idx >> 5, c = idx & 31;
            int node = min(blkBase + r, NN - 1);
            const float* p = &emb[(size_t)node * DD + t * 128 + c * 4];
            asm volatile("global_load_dwordx4 %0, %1, off"
                         : "=v"(aregs[i]) : "v"(p));
        }
    };
    auto writeLDS = [&]() {
        asm volatile("s_waitcnt vmcnt(0)" ::: "memory");
        __builtin_amdgcn_sched_barrier(0);
#pragma unroll
        for (int i = 0; i < 8; ++i) {
            int idx = tid + i * 256;
            int r = idx >> 5, c = idx & 31;
            ushort4 hv, lv;
            split_bf16(aregs[i].x, hv.x, lv.x);
            split_bf16(aregs[i].y, hv.y, lv.y);
            split_bf16(aregs[i].z, hv.z, lv.z);
            split_bf16(aregs[i].w, hv.w, lv.w);
            int byte = (r * 256 + c * 8) ^ ((r & 7) << 4);
            *reinterpret_cast<ushort4*>(reinterpret_cast<char*>(Ah) + byte) = hv;
            *reinterpret_cast<ushort4*>(reinterpret_cast<char*>(Al) + byte) = lv;
        }
    };

    issueA(0);
    writeLDS();
    __syncthreads();

#pragma unroll
    for (int t = 0; t < 3; ++t) {
        if (t < 2) issueA(t + 1);  // pinned in flight across the whole compute phase

        short8 bh[2][4], bl[2][4], ah[2][2], al[2][2];
        auto loadB = [&](int kt, int s) {
            int ks = t * 4 + kt;
#pragma unroll
            for (int nt = 0; nt < 4; ++nt) {
                size_t off = ((size_t)((wn * 4 + nt) * 12 + ks) * 64 + lane) * 8;
                bh[s][nt] = *reinterpret_cast<const short8*>(&W1h[off]);
                bl[s][nt] = *reinterpret_cast<const short8*>(&W1l[off]);
            }
        };
        auto loadA = [&](int kt, int s) {
#pragma unroll
            for (int mt = 0; mt < 2; ++mt) {
                int row = wm * 32 + mt * 16 + (lane & 15);
                int byte = (row * 256 + kt * 64 + ((lane >> 4) << 4)) ^ ((row & 7) << 4);
                ah[s][mt] = *reinterpret_cast<const short8*>(reinterpret_cast<const char*>(Ah) + byte);
                al[s][mt] = *reinterpret_cast<const short8*>(reinterpret_cast<const char*>(Al) + byte);
            }
        };

        loadB(0, 0);
        loadA(0, 0);
#pragma unroll
        for (int kt = 0; kt < 4; ++kt) {
            const int cur = kt & 1, nxt = cur ^ 1;
            if (kt < 3) {
                loadB(kt + 1, nxt);
                loadA(kt + 1, nxt);
            }
#pragma unroll
            for (int mt = 0; mt < 2; ++mt)
#pragma unroll
                for (int nt = 0; nt < 4; ++nt) {
                    acc[mt][nt] = __builtin_amdgcn_mfma_f32_16x16x32_bf16(ah[cur][mt], bh[cur][nt], acc[mt][nt], 0, 0, 0);
                    acc[mt][nt] = __builtin_amdgcn_mfma_f32_16x16x32_bf16(al[cur][mt], bh[cur][nt], acc[mt][nt], 0, 0, 0);
                    acc[mt][nt] = __builtin_amdgcn_mfma_f32_16x16x32_bf16(ah[cur][mt], bl[cur][nt], acc[mt][nt], 0, 0, 0);
                }
        }

        if (t < 2) {
            __syncthreads();   // all waves done reading tile t
            writeLDS();        // vmcnt(0) wait lands here, hidden by compute above
            __syncthreads();
        }
    }

    // epilogue: v = relu(h + b1p); p[j] = sum_h v * W2[h][j]; reduce over 16 lanes
    float b1v[4], w2v[4][KK];
#pragma unroll
    for (int nt = 0; nt < 4; ++nt) {
        int h = wn * 64 + nt * 16 + (lane & 15);
        b1v[nt] = b1p[h];
#pragma unroll
        for (int j = 0; j < KK; ++j) w2v[nt][j] = W2[h * KK + j];
    }
#pragma unroll
    for (int mt = 0; mt < 2; ++mt) {
        float p[4][KK];
#pragma unroll
        for (int r = 0; r < 4; ++r)
#pragma unroll
            for (int j = 0; j < KK; ++j) p[r][j] = 0.f;
#pragma unroll
        for (int nt = 0; nt < 4; ++nt)
#pragma unroll
            for (int r = 0; r < 4; ++r) {
                float v = fmaxf(acc[mt][nt][r] + b1v[nt], 0.f);
#pragma unroll
                for (int j = 0; j < KK; ++j) p[r][j] = fmaf(v, w2v[nt][j], p[r][j]);
            }
#pragma unroll
        for (int off = 1; off < 16; off <<= 1)
#pragma unroll
            for (int r = 0; r < 4; ++r)
#pragma unroll
                for (int j = 0; j < KK; ++j) p[r][j] += __shfl_xor(p[r][j], off, 64);
        if ((lane & 15) == 0) {
            int rowbase = wm * 32 + mt * 16 + (lane >> 4) * 4;
#pragma unroll
            for (int r = 0; r < 4; ++r)
#pragma unroll
                for (int j = 0; j < KK; ++j) pbuf[rowbase + r][wn][j] = p[r][j];
        }
    }
    __syncthreads();
    if (tid < 64) {
        int node = blkBase + tid;
        if (node < NN) {
            float a[KK], an2 = 0.f;
#pragma unroll
            for (int j = 0; j < KK; ++j) {
                a[j] = pbuf[tid][0][j] + pbuf[tid][1][j] + b2[j];
                an2 = fmaf(a[j], a[j], an2);
            }
            float an = sqrtf(an2);
            bool valid = (an2 > 0.f) && isfinite(an);
            float g5[KK], ssum = 0.f;
#pragma unroll
            for (int j = 0; j < KK; ++j) {
                g5[j] = valid ? (a[j] / an) : RSQRT5;
                gout[j * NN + node] = g5[j];
                ssum += g5[j];
            }
            // fused walk step 1: state uniform INIT_VAL -> d = INIT * sum(g)
            float d = ssum * INIT_VAL;
#pragma unroll
            for (int j = 0; j < KK; ++j)
                atomicAdd(&sA[j * NN + nbrT[j * NN + node]], g5[j] * d);
        }
    }
}

// ---------------- walk step: s_p = g (g.u); scatter-add ----------------
__global__ void walk_step_kernel(const float* __restrict__ g, const int* __restrict__ nbrT,
                                 const float* __restrict__ u, float* __restrict__ v) {
    int i = blockIdx.x * blockDim.x + threadIdx.x;
    if (i >= NN) return;
    float gj[KK], d = 0.f;
#pragma unroll
    for (int j = 0; j < KK; ++j) {
        gj[j] = g[j * NN + i];
        d = fmaf(gj[j], u[j * NN + i], d);
    }
#pragma unroll
    for (int j = 0; j < KK; ++j)
        atomicAdd(&v[j * NN + nbrT[j * NN + i]], gj[j] * d);
}

// ---------------- global sum of squares (float4) ----------------
__global__ void norm_reduce_kernel(const float* __restrict__ u, float* __restrict__ ss) {
    int i = blockIdx.x * blockDim.x + threadIdx.x;
    const int total4 = (KK * NN) / 4;  // 125000
    float s = 0.f;
    for (int idx = i; idx < total4; idx += gridDim.x * blockDim.x) {
        float4 x = reinterpret_cast<const float4*>(u)[idx];
        s = fmaf(x.x, x.x, s);
        s = fmaf(x.y, x.y, s);
        s = fmaf(x.z, x.z, s);
        s = fmaf(x.w, x.w, s);
    }
#pragma unroll
    for (int off = 32; off > 0; off >>= 1) s += __shfl_xor(s, off, 64);
    if ((threadIdx.x & 63) == 0) atomicAdd(ss, s);
}

// ---------------- out[i] = sum_j |u[j][i]| / ||u|| ----------------
__global__ void finalize_kernel(const float* __restrict__ u, const float* __restrict__ ss,
                                float* __restrict__ out) {
    int i = blockIdx.x * blockDim.x + threadIdx.x;
    if (i >= NN) return;
    float s = 0.f;
#pragma unroll
    for (int j = 0; j < KK; ++j) s += fabsf(u[j * NN + i]);
    float nrm = sqrtf(*ss);
    out[i] = (nrm > 0.f) ? (s / nrm) : (KK * INIT_VAL);
}

extern "C" void kernel_launch(void* const* d_in, const int* in_sizes, int n_in,
                              void* d_out, int out_size, void* d_ws, size_t ws_size,
                              hipStream_t stream) {
    const float* emb = (const float*)d_in[0];
    const float* qv  = (const float*)d_in[1];
    const float* W1  = (const float*)d_in[2];
    const float* b1  = (const float*)d_in[3];
    const float* W2  = (const float*)d_in[4];
    const float* b2  = (const float*)d_in[5];
    const int*   nbr = (const int*)d_in[6];
    float* out = (float*)d_out;

    char* ws = (char*)d_ws;
    size_t off = 0;
    auto alloc = [&](size_t bytes) {
        char* p = ws + off;
        off += (bytes + 255) & ~(size_t)255;
        return p;
    };
    float*  b1p  = (float*)alloc(HH * sizeof(float));
    ushort* W1h  = (ushort*)alloc((size_t)DD * HH * sizeof(ushort));
    ushort* W1l  = (ushort*)alloc((size_t)DD * HH * sizeof(ushort));
    float*  gbuf = (float*)alloc((size_t)KK * NN * sizeof(float));
    int*    nbrT = (int*)  alloc((size_t)KK * NN * sizeof(int));
    float*  sA   = (float*)alloc((size_t)KK * NN * sizeof(float));
    float*  sB   = (float*)alloc((size_t)KK * NN * sizeof(float));
    float*  sC   = (float*)alloc((size_t)KK * NN * sizeof(float));
    float*  ssp  = (float*)alloc(sizeof(float));

    const int nblk = (NN + 255) / 256;   // 391

    prep_kernel<<<25 + nblk, 256, 0, stream>>>(qv, W1, b1, nbr, b1p, W1h, W1l,
                                               nbrT, sA, sB, sC, ssp);
    // mlp computes g AND performs walk step 1 (scatter into sA)
    mlp_mfma_kernel<<<(NN + 63) / 64, 256, 0, stream>>>(emb, W1h, W1l, b1p, W2, b2,
                                                        nbrT, gbuf, sA);

    walk_step_kernel<<<nblk, 256, 0, stream>>>(gbuf, nbrT, sA, sB);
    walk_step_kernel<<<nblk, 256, 0, stream>>>(gbuf, nbrT, sB, sC);

    norm_reduce_kernel<<<512, 256, 0, stream>>>(sC, ssp);
    finalize_kernel<<<nblk, 256, 0, stream>>>(sC, ssp, out);
}